// Round 1
// baseline (201.770 us; speedup 1.0000x reference)
//
#include <hip/hip_runtime.h>

// TwoTwoNet: rank-2 recurrence collapse.
// State s[b,:] after any step is mask * clip(alpha*dec + beta*enc, -1, 1),
// so the full [B,n] state never needs to exist. Per (batch, step) we need
// three n-length dot products of the clipped rank-2 vector against
// (mask*dec), (mask*enc), (mask*decoder).
//
// Layout: 1 wave (64 lanes) per batch. 16 channels per lane held in VGPRs.
// No LDS, no __syncthreads. Wave all-reduce via __shfl_xor butterfly.

constexpr int Bc  = 256;
constexpr int Tc  = 512;
constexpr int Nc  = 1024;
constexpr int EPL = Nc / 64;   // 16 channels per lane

__device__ __forceinline__ void allreduce3(float& a, float& b, float& c) {
#pragma unroll
    for (int m = 32; m >= 1; m >>= 1) {
        a += __shfl_xor(a, m, 64);
        b += __shfl_xor(b, m, 64);
        c += __shfl_xor(c, m, 64);
    }
}

__device__ __forceinline__ void allreduce4(float& a, float& b, float& c, float& d) {
#pragma unroll
    for (int m = 32; m >= 1; m >>= 1) {
        a += __shfl_xor(a, m, 64);
        b += __shfl_xor(b, m, 64);
        c += __shfl_xor(c, m, 64);
        d += __shfl_xor(d, m, 64);
    }
}

__global__ __launch_bounds__(64) void twotwonet_kernel(
    const float* __restrict__ x,        // [B, T]
    const float* __restrict__ state0,   // [n]
    const float* __restrict__ mask,     // [n]
    const float* __restrict__ w,        // [2,2] row-major
    const float* __restrict__ dec_orth, // [n]
    const float* __restrict__ enc_orth, // [n]
    const float* __restrict__ decoder,  // [n]
    const float* __restrict__ encoder,  // [n]
    float* __restrict__ out)            // [B, T]
{
    const int b    = blockIdx.x;
    const int lane = threadIdx.x;   // 0..63

    // Per-lane channel slices, fully register resident.
    float d[EPL], e[EPL], wd[EPL], we[EPL], wo[EPL];

    float s0d = 0.f, s0e = 0.f, kd = 0.f, ke = 0.f;
#pragma unroll
    for (int k = 0; k < EPL; ++k) {
        const int c = lane + 64 * k;
        const float dv   = dec_orth[c];
        const float ev   = enc_orth[c];
        const float mv   = mask[c];
        const float encv = encoder[c];
        const float decv = decoder[c];
        const float s0v  = state0[c];
        d[k]  = dv;
        e[k]  = ev;
        wd[k] = mv * dv;
        we[k] = mv * ev;
        wo[k] = mv * decv;
        s0d += s0v * dv;            // <state0, dec>
        s0e += s0v * ev;            // <state0, enc>
        kd  = fmaf(mv * encv, dv, kd);  // <mask*encoder, dec>
        ke  = fmaf(mv * encv, ev, ke);  // <mask*encoder, enc>
    }
    allreduce4(s0d, s0e, kd, ke);

    const float w00 = w[0], w01 = w[1], w10 = w[2], w11 = w[3];

    float Sd = s0d;                 // <s_prev, dec>
    float Se = s0e;                 // <s_prev, enc>

    const float* xrow = x + (size_t)b * Tc;
    float xt = xrow[0];
    float obuf = 0.f;

    for (int t = 0; t < Tc; ++t) {
        // Prefetch next x (wave-uniform load; hidden under this step's compute).
        const int tn = (t + 1 < Tc) ? (t + 1) : t;
        const float xnext = xrow[tn];

        const float p = fmaf(xt, kd, Sd);
        const float q = fmaf(xt, ke, Se);
        const float alpha = fmaf(w01, q, w00 * p);
        const float beta  = fmaf(w11, q, w10 * p);

        float ad = 0.f, ae = 0.f, ao = 0.f;
#pragma unroll
        for (int k = 0; k < EPL; ++k) {
            float v = fmaf(beta, e[k], alpha * d[k]);
            v = __builtin_amdgcn_fmed3f(v, -1.0f, 1.0f);   // clip(v,-1,1)
            ad = fmaf(v, wd[k], ad);
            ae = fmaf(v, we[k], ae);
            ao = fmaf(v, wo[k], ao);
        }
        allreduce3(ad, ae, ao);

        Sd = ad;
        Se = ae;

        // Buffer one output per step in the matching lane; coalesced store
        // of 64 outputs every 64 steps.
        obuf = ((t & 63) == lane) ? ao : obuf;
        if ((t & 63) == 63) {
            out[(size_t)b * Tc + (t - 63) + lane] = obuf;
        }
        xt = xnext;
    }
}

extern "C" void kernel_launch(void* const* d_in, const int* in_sizes, int n_in,
                              void* d_out, int out_size, void* d_ws, size_t ws_size,
                              hipStream_t stream) {
    const float* x        = (const float*)d_in[0];
    const float* state0   = (const float*)d_in[1];
    const float* mask     = (const float*)d_in[2];
    const float* w        = (const float*)d_in[3];
    const float* dec_orth = (const float*)d_in[4];
    const float* enc_orth = (const float*)d_in[5];
    const float* decoder  = (const float*)d_in[6];
    const float* encoder  = (const float*)d_in[7];
    float* out = (float*)d_out;

    twotwonet_kernel<<<dim3(Bc), dim3(64), 0, stream>>>(
        x, state0, mask, w, dec_orth, enc_orth, decoder, encoder, out);
}

// Round 3
// 130.569 us; speedup vs baseline: 1.5453x; 1.5453x over previous
//
#include <hip/hip_runtime.h>

// TwoTwoNet: rank-2 recurrence collapse.
// s[b,:] = mask * clip(alpha*dec + beta*enc) always, so per (batch,step) we
// only need 3 dot products of the clipped rank-2 vector against
// (mask*dec), (mask*enc), (mask*decoder). 1 wave per batch, 16 ch/lane in
// VGPRs, inner math packed fp32 (v_pk_fma_f32), wave reduce via DPP
// (row_shr + row_bcast -> lane 63 -> v_readlane), no LDS in the hot loop.

typedef float f32x2 __attribute__((ext_vector_type(2)));

constexpr int Bc  = 256;
constexpr int Tc  = 512;
constexpr int Nc  = 1024;
constexpr int EPL = Nc / 64;   // 16 channels per lane
constexpr int PPL = EPL / 2;   // 8 packed float2 per lane

template <int CTRL, int RMASK>
__device__ __forceinline__ float dpp_add(float v) {
    // bound_ctrl=true: masked-off/invalid source lanes read 0 -> v unchanged
    int t = __builtin_amdgcn_update_dpp(0, __float_as_int(v), CTRL, RMASK, 0xf, true);
    return v + __int_as_float(t);
}

// Full 64-lane sum; result valid in lane 63 (classic GCN DPP reduction).
__device__ __forceinline__ float wave_sum63(float v) {
    v = dpp_add<0x111, 0xf>(v);  // row_shr:1
    v = dpp_add<0x112, 0xf>(v);  // row_shr:2
    v = dpp_add<0x114, 0xf>(v);  // row_shr:4
    v = dpp_add<0x118, 0xf>(v);  // row_shr:8  -> lane15 of each row = row sum
    v = dpp_add<0x142, 0xa>(v);  // row_bcast:15 into rows 1,3
    v = dpp_add<0x143, 0xc>(v);  // row_bcast:31 into rows 2,3 -> lane63 total
    return v;
}

__device__ __forceinline__ float readlane63(float v) {
    return __int_as_float(__builtin_amdgcn_readlane(__float_as_int(v), 63));
}

__global__ __launch_bounds__(64) void twotwonet_kernel(
    const float* __restrict__ x,        // [B, T]
    const float* __restrict__ state0,   // [n]
    const float* __restrict__ mask,     // [n]
    const float* __restrict__ w,        // [2,2]
    const float* __restrict__ dec_orth, // [n]
    const float* __restrict__ enc_orth, // [n]
    const float* __restrict__ decoder,  // [n]
    const float* __restrict__ encoder,  // [n]
    float* __restrict__ out)            // [B, T]
{
    const int b    = blockIdx.x;
    const int lane = threadIdx.x;   // 0..63

    // Per-lane channel slices, packed 2-wide, fully register resident.
    f32x2 d2[PPL], e2[PPL], wd2[PPL], we2[PPL], wo2[PPL];

    float s0d = 0.f, s0e = 0.f, kd = 0.f, ke = 0.f;
#pragma unroll
    for (int j = 0; j < PPL; ++j) {
#pragma unroll
        for (int h = 0; h < 2; ++h) {
            const int c = lane + 64 * (2 * j + h);
            const float dv   = dec_orth[c];
            const float ev   = enc_orth[c];
            const float mv   = mask[c];
            const float encv = encoder[c];
            const float decv = decoder[c];
            const float s0v  = state0[c];
            d2[j][h]  = dv;
            e2[j][h]  = ev;
            wd2[j][h] = mv * dv;
            we2[j][h] = mv * ev;
            wo2[j][h] = mv * decv;
            s0d += s0v * dv;
            s0e += s0v * ev;
            kd  = fmaf(mv * encv, dv, kd);
            ke  = fmaf(mv * encv, ev, ke);
        }
    }
    // cold-path init reduce (runs once) — shfl is fine here
#pragma unroll
    for (int m = 32; m >= 1; m >>= 1) {
        s0d += __shfl_xor(s0d, m, 64);
        s0e += __shfl_xor(s0e, m, 64);
        kd  += __shfl_xor(kd, m, 64);
        ke  += __shfl_xor(ke, m, 64);
    }

    const float w00 = w[0], w01 = w[1], w10 = w[2], w11 = w[3];

    float Sd = s0d;                 // <s_prev, dec>
    float Se = s0e;                 // <s_prev, enc>

    const float* xrow = x + (size_t)b * Tc;
    float xt  = xrow[0];
    float xp1 = xrow[1];
    float obuf = 0.f;

    for (int t = 0; t < Tc; ++t) {
        // 2-deep uniform prefetch
        const int tn = (t + 2 < Tc) ? (t + 2) : (Tc - 1);
        const float xnext = xrow[tn];

        const float p = fmaf(xt, kd, Sd);
        const float q = fmaf(xt, ke, Se);
        const float alpha = fmaf(w01, q, w00 * p);
        const float beta  = fmaf(w11, q, w10 * p);
        const f32x2 a2 = {alpha, alpha};
        const f32x2 b2 = {beta, beta};

        f32x2 accd = {0.f, 0.f}, acce = {0.f, 0.f}, acco = {0.f, 0.f};
#pragma unroll
        for (int j = 0; j < PPL; ++j) {
            f32x2 v = a2 * d2[j] + b2 * e2[j];     // pk_mul + pk_fma (contract)
            v.x = __builtin_amdgcn_fmed3f(v.x, -1.0f, 1.0f);
            v.y = __builtin_amdgcn_fmed3f(v.y, -1.0f, 1.0f);
            accd += v * wd2[j];                     // pk_fma
            acce += v * we2[j];
            acco += v * wo2[j];
        }
        float ad = accd.x + accd.y;
        float ae = acce.x + acce.y;
        float ao = acco.x + acco.y;

        // three independent DPP chains interleave to hide dep latency
        ad = wave_sum63(ad);
        ae = wave_sum63(ae);
        ao = wave_sum63(ao);

        Sd = readlane63(ad);
        Se = readlane63(ae);
        const float aou = readlane63(ao);

        obuf = ((t & 63) == lane) ? aou : obuf;
        if ((t & 63) == 63) {
            out[(size_t)b * Tc + (t - 63) + lane] = obuf;
        }
        xt = xp1;
        xp1 = xnext;
    }
}

extern "C" void kernel_launch(void* const* d_in, const int* in_sizes, int n_in,
                              void* d_out, int out_size, void* d_ws, size_t ws_size,
                              hipStream_t stream) {
    const float* x        = (const float*)d_in[0];
    const float* state0   = (const float*)d_in[1];
    const float* mask     = (const float*)d_in[2];
    const float* w        = (const float*)d_in[3];
    const float* dec_orth = (const float*)d_in[4];
    const float* enc_orth = (const float*)d_in[5];
    const float* decoder  = (const float*)d_in[6];
    const float* encoder  = (const float*)d_in[7];
    float* out = (float*)d_out;

    twotwonet_kernel<<<dim3(Bc), dim3(64), 0, stream>>>(
        x, state0, mask, w, dec_orth, enc_orth, decoder, encoder, out);
}

// Round 4
// 116.473 us; speedup vs baseline: 1.7323x; 1.1210x over previous
//
#include <hip/hip_runtime.h>

// TwoTwoNet: rank-2 recurrence collapse, round 3.
// State after any step is s = mask*clip(alpha*dec+beta*enc), so we carry only
// (alpha_u, beta, sigma_d, sigma_e) with Sd = alpha_u*sigma_d.
// Inner trick: v = clip(a*d+b*e,-1,1) == au * med3(d + (b/au)*e, -|1/au|, +|1/au|)
// exactly (both signs of au), with au = copysign(max(|a|,1e-20),a).
// So the 1024-channel pass is 6 VALU per 2 channels (pk_fma, 2x med3, 3x pk_fma)
// and alpha folds into the scalar state update.
// x[b,:] preloaded into 8 VGPRs, per-step broadcast via v_readlane (dynamic lane).
// Wave reduce: DPP row_shr/row_bcast chain -> lane 63 -> readlane -> SGPR.

typedef float f32x2 __attribute__((ext_vector_type(2)));

constexpr int Bc  = 256;
constexpr int Tc  = 512;
constexpr int Nc  = 1024;
constexpr int EPL = Nc / 64;   // 16 channels per lane
constexpr int PPL = EPL / 2;   // 8 packed float2 per lane
constexpr int CH  = Tc / 64;   // 8 chunks of 64 steps

template <int CTRL, int RMASK>
__device__ __forceinline__ float dpp_add(float v) {
    int t = __builtin_amdgcn_update_dpp(0, __float_as_int(v), CTRL, RMASK, 0xf, true);
    return v + __int_as_float(t);
}

// Full 64-lane sum; result valid in lane 63.
__device__ __forceinline__ float wave_sum63(float v) {
    v = dpp_add<0x111, 0xf>(v);  // row_shr:1
    v = dpp_add<0x112, 0xf>(v);  // row_shr:2
    v = dpp_add<0x114, 0xf>(v);  // row_shr:4
    v = dpp_add<0x118, 0xf>(v);  // row_shr:8
    v = dpp_add<0x142, 0xa>(v);  // row_bcast:15 -> rows 1,3
    v = dpp_add<0x143, 0xc>(v);  // row_bcast:31 -> rows 2,3 (lane63 = total)
    return v;
}

__device__ __forceinline__ float readlane_f(float v, int lane) {
    return __int_as_float(__builtin_amdgcn_readlane(__float_as_int(v), lane));
}

__global__ __launch_bounds__(64) void twotwonet_kernel(
    const float* __restrict__ x,        // [B, T]
    const float* __restrict__ state0,   // [n]
    const float* __restrict__ mask,     // [n]
    const float* __restrict__ w,        // [2,2]
    const float* __restrict__ dec_orth, // [n]
    const float* __restrict__ enc_orth, // [n]
    const float* __restrict__ decoder,  // [n]
    const float* __restrict__ encoder,  // [n]
    float* __restrict__ out)            // [B, T]
{
    const int b    = blockIdx.x;
    const int lane = threadIdx.x;   // 0..63

    // Per-lane channel slices, packed 2-wide, fully register resident.
    f32x2 d2[PPL], e2[PPL], wd2[PPL], we2[PPL], wo2[PPL];

    float s0d = 0.f, s0e = 0.f, kd = 0.f, ke = 0.f;
#pragma unroll
    for (int j = 0; j < PPL; ++j) {
#pragma unroll
        for (int h = 0; h < 2; ++h) {
            const int c = lane + 64 * (2 * j + h);
            const float dv   = dec_orth[c];
            const float ev   = enc_orth[c];
            const float mv   = mask[c];
            const float encv = encoder[c];
            const float decv = decoder[c];
            const float s0v  = state0[c];
            d2[j][h]  = dv;
            e2[j][h]  = ev;
            wd2[j][h] = mv * dv;
            we2[j][h] = mv * ev;
            wo2[j][h] = mv * decv;
            s0d += s0v * dv;
            s0e += s0v * ev;
            kd  = fmaf(mv * encv, dv, kd);
            ke  = fmaf(mv * encv, ev, ke);
        }
    }
    // cold-path init reduce (runs once)
#pragma unroll
    for (int m = 32; m >= 1; m >>= 1) {
        s0d += __shfl_xor(s0d, m, 64);
        s0e += __shfl_xor(s0e, m, 64);
        kd  += __shfl_xor(kd, m, 64);
        ke  += __shfl_xor(ke, m, 64);
    }

    const float w00 = w[0], w01 = w[1], w10 = w[2], w11 = w[3];
    const float A1 = w00 * kd + w01 * ke;   // x-coupling for alpha
    const float A2 = w10 * kd + w11 * ke;   // x-coupling for beta

    // Preload this batch's entire x row: 8 regs, 64 steps each.
    const float* xrow = x + (size_t)b * Tc;
    float xr[CH];
#pragma unroll
    for (int c = 0; c < CH; ++c) xr[c] = xrow[lane + 64 * c];

    // Carried state: Sd_true = au*sd, Se_true = au*se (au=1 initially).
    float au = 1.0f;
    float sd = s0d;   // uniform VGPR
    float se = s0e;

#pragma unroll
    for (int c = 0; c < CH; ++c) {
        float obuf = 0.f;
        for (int t2 = 0; t2 < 64; ++t2) {
            const float xs = readlane_f(xr[c], t2);

            // alpha = au*(w00*sd + w01*se) + x*A1 ; beta likewise
            const float q1 = fmaf(w00, sd, w01 * se);
            const float q2 = fmaf(w10, sd, w11 * se);
            const float alpha = fmaf(xs, A1, au * q1);
            const float beta  = fmaf(xs, A2, au * q2);

            // guard + fold: au = copysign(max(|alpha|,1e-20), alpha)
            const float aa = fmaxf(fabsf(alpha), 1e-20f);
            au = copysignf(aa, alpha);
            const float inv = __builtin_amdgcn_rcpf(au);   // ~1ulp approx ok
            const float r   = beta * inv;
            const float bb  = fabsf(inv);                  // clip bound
            const f32x2 r2  = {r, r};

            f32x2 accd = {0.f, 0.f}, acce = {0.f, 0.f}, acco = {0.f, 0.f};
#pragma unroll
            for (int j = 0; j < PPL; ++j) {
                f32x2 tt = r2 * e2[j] + d2[j];                     // pk_fma
                f32x2 m;
                m.x = __builtin_amdgcn_fmed3f(tt.x, -bb, bb);      // modifiers free
                m.y = __builtin_amdgcn_fmed3f(tt.y, -bb, bb);
                accd += m * wd2[j];
                acce += m * we2[j];
                acco += m * wo2[j];
            }
            float ad = accd.x + accd.y;
            float ae = acce.x + acce.y;
            float ao = acco.x + acco.y;

            ad = wave_sum63(ad);
            ae = wave_sum63(ae);
            ao = wave_sum63(ao);

            sd = readlane_f(ad, 63);   // sigma_d (uniform)
            se = readlane_f(ae, 63);
            const float so = readlane_f(ao, 63);

            const float ov = au * so;  // out_t = au * sigma_o
            obuf = (t2 == lane) ? ov : obuf;
        }
        out[(size_t)b * Tc + 64 * c + lane] = obuf;
    }
}

extern "C" void kernel_launch(void* const* d_in, const int* in_sizes, int n_in,
                              void* d_out, int out_size, void* d_ws, size_t ws_size,
                              hipStream_t stream) {
    const float* x        = (const float*)d_in[0];
    const float* state0   = (const float*)d_in[1];
    const float* mask     = (const float*)d_in[2];
    const float* w        = (const float*)d_in[3];
    const float* dec_orth = (const float*)d_in[4];
    const float* enc_orth = (const float*)d_in[5];
    const float* decoder  = (const float*)d_in[6];
    const float* encoder  = (const float*)d_in[7];
    float* out = (float*)d_out;

    twotwonet_kernel<<<dim3(Bc), dim3(64), 0, stream>>>(
        x, state0, mask, w, dec_orth, enc_orth, decoder, encoder, out);
}

// Round 5
// 114.360 us; speedup vs baseline: 1.7643x; 1.0185x over previous
//
#include <hip/hip_runtime.h>

// TwoTwoNet: rank-2 recurrence collapse, round 4.
// Carry (au, q1, q2) where alpha = au*q1 + x*A1, beta = au*q2 + x*A2, and
// per step do one 1024-channel pass: m = med3(d + (beta/au)*e, -|1/au|, +|1/au|),
// accumulate 3 dots (mask*d, mask*e, mask*decoder), DPP-reduce to lane 63,
// fold W into lane 63, readlane-broadcast. All tables in NAMED f32x2 registers
// (arrays were being demoted: VGPR_Count=64 < 80 live floats => scratch/L1
// round-trips dominated R3). __launch_bounds__(64,1) frees the register budget.

typedef float f32x2 __attribute__((ext_vector_type(2)));

constexpr int Bc = 256;
constexpr int Tc = 512;
constexpr int CH = Tc / 64;   // 8 chunks of 64 steps

template <int CTRL, int RMASK>
__device__ __forceinline__ float dpp_add(float v) {
    int t = __builtin_amdgcn_update_dpp(0, __float_as_int(v), CTRL, RMASK, 0xf, true);
    return v + __int_as_float(t);
}

// Full 64-lane sum; result valid in lane 63.
__device__ __forceinline__ float wave_sum63(float v) {
    v = dpp_add<0x111, 0xf>(v);  // row_shr:1
    v = dpp_add<0x112, 0xf>(v);  // row_shr:2
    v = dpp_add<0x114, 0xf>(v);  // row_shr:4
    v = dpp_add<0x118, 0xf>(v);  // row_shr:8
    v = dpp_add<0x142, 0xa>(v);  // row_bcast:15 -> rows 1,3
    v = dpp_add<0x143, 0xc>(v);  // row_bcast:31 -> rows 2,3
    return v;
}

__device__ __forceinline__ float readlane_f(float v, int l) {
    return __int_as_float(__builtin_amdgcn_readlane(__float_as_int(v), l));
}

#define DECL_TBL(i) f32x2 d2_##i, e2_##i, wd2_##i, we2_##i, wo2_##i

#define INIT_TBL(i) do { \
    _Pragma("unroll") \
    for (int h = 0; h < 2; ++h) { \
        const int c = lane + 64 * (2 * (i) + h); \
        const float dv   = dec_orth[c]; \
        const float ev   = enc_orth[c]; \
        const float mv   = mask[c]; \
        const float encv = encoder[c]; \
        const float decv = decoder[c]; \
        const float s0v  = state0[c]; \
        d2_##i[h]  = dv;  e2_##i[h]  = ev; \
        wd2_##i[h] = mv * dv; we2_##i[h] = mv * ev; wo2_##i[h] = mv * decv; \
        s0d += s0v * dv;  s0e += s0v * ev; \
        kd = fmaf(mv * encv, dv, kd); \
        ke = fmaf(mv * encv, ev, ke); \
    } \
} while (0)

#define ACC_J(i) do { \
    f32x2 tt = r2 * e2_##i + d2_##i;                    /* pk_fma */ \
    f32x2 mm; \
    mm.x = __builtin_amdgcn_fmed3f(tt.x, -bb, bb); \
    mm.y = __builtin_amdgcn_fmed3f(tt.y, -bb, bb); \
    accd += mm * wd2_##i; \
    acce += mm * we2_##i; \
    acco += mm * wo2_##i; \
} while (0)

__global__ __launch_bounds__(64, 1) void twotwonet_kernel(
    const float* __restrict__ x,        // [B, T]
    const float* __restrict__ state0,   // [n]
    const float* __restrict__ mask,     // [n]
    const float* __restrict__ w,        // [2,2]
    const float* __restrict__ dec_orth, // [n]
    const float* __restrict__ enc_orth, // [n]
    const float* __restrict__ decoder,  // [n]
    const float* __restrict__ encoder,  // [n]
    float* __restrict__ out)            // [B, T]
{
    const int b    = blockIdx.x;
    const int lane = threadIdx.x;   // 0..63

    DECL_TBL(0); DECL_TBL(1); DECL_TBL(2); DECL_TBL(3);
    DECL_TBL(4); DECL_TBL(5); DECL_TBL(6); DECL_TBL(7);

    float s0d = 0.f, s0e = 0.f, kd = 0.f, ke = 0.f;
    INIT_TBL(0); INIT_TBL(1); INIT_TBL(2); INIT_TBL(3);
    INIT_TBL(4); INIT_TBL(5); INIT_TBL(6); INIT_TBL(7);

    // cold-path init reduce (runs once)
#pragma unroll
    for (int m = 32; m >= 1; m >>= 1) {
        s0d += __shfl_xor(s0d, m, 64);
        s0e += __shfl_xor(s0e, m, 64);
        kd  += __shfl_xor(kd, m, 64);
        ke  += __shfl_xor(ke, m, 64);
    }

    const float w00 = w[0], w01 = w[1], w10 = w[2], w11 = w[3];
    const float A1 = w00 * kd + w01 * ke;   // x-coupling for alpha
    const float A2 = w10 * kd + w11 * ke;   // x-coupling for beta

    // Preload this batch's entire x row: 8 regs, 64 steps each.
    const float* xrow = x + (size_t)b * Tc;
    float xr[CH];
#pragma unroll
    for (int c = 0; c < CH; ++c) xr[c] = xrow[lane + 64 * c];

    // Carried state: alpha = au*q1 + x*A1, beta = au*q2 + x*A2.
    float au = 1.0f;
    float q1 = fmaf(w00, s0d, w01 * s0e);
    float q2 = fmaf(w10, s0d, w11 * s0e);

#pragma unroll
    for (int c = 0; c < CH; ++c) {
        float obuf = 0.f;
#pragma unroll 2
        for (int t2 = 0; t2 < 64; ++t2) {
            const float xs = readlane_f(xr[c], t2);

            const float alpha = fmaf(au, q1, xs * A1);
            const float beta  = fmaf(au, q2, xs * A2);

            // au = copysign(max(|alpha|, eps), alpha); inv = 1/au
            const float aun = copysignf(fmaxf(fabsf(alpha), 1e-20f), alpha);
            const float inv = __builtin_amdgcn_rcpf(aun);
            const float r   = beta * inv;
            const float bb  = fabsf(inv);
            const f32x2 r2  = {r, r};

            f32x2 accd = {0.f, 0.f}, acce = {0.f, 0.f}, acco = {0.f, 0.f};
            ACC_J(0); ACC_J(1); ACC_J(2); ACC_J(3);
            ACC_J(4); ACC_J(5); ACC_J(6); ACC_J(7);

            float ad = accd.x + accd.y;
            float ae = acce.x + acce.y;
            float ao = acco.x + acco.y;

            // three independent DPP chains interleave to hide dep latency
            ad = wave_sum63(ad);
            ae = wave_sum63(ae);
            ao = wave_sum63(ao);

            // fold the 2x2 W head into lane 63 BEFORE the broadcast
            const float q1n = fmaf(w00, ad, w01 * ae);
            const float q2n = fmaf(w10, ad, w11 * ae);
            q1 = readlane_f(q1n, 63);
            q2 = readlane_f(q2n, 63);
            const float so = readlane_f(ao, 63);
            au = aun;

            const float ov = aun * so;       // out_t = au * sigma_o
            obuf = (t2 == lane) ? ov : obuf;
        }
        out[(size_t)b * Tc + 64 * c + lane] = obuf;
    }
}

extern "C" void kernel_launch(void* const* d_in, const int* in_sizes, int n_in,
                              void* d_out, int out_size, void* d_ws, size_t ws_size,
                              hipStream_t stream) {
    const float* x        = (const float*)d_in[0];
    const float* state0   = (const float*)d_in[1];
    const float* mask     = (const float*)d_in[2];
    const float* w        = (const float*)d_in[3];
    const float* dec_orth = (const float*)d_in[4];
    const float* enc_orth = (const float*)d_in[5];
    const float* decoder  = (const float*)d_in[6];
    const float* encoder  = (const float*)d_in[7];
    float* out = (float*)d_out;

    twotwonet_kernel<<<dim3(Bc), dim3(64), 0, stream>>>(
        x, state0, mask, w, dec_orth, enc_orth, decoder, encoder, out);
}